// Round 1
// baseline (99.321 us; speedup 1.0000x reference)
//
#include <hip/hip_runtime.h>

#define Bn 2
#define Cn 3
#define Hn 160
#define Wn 160
#define SPANc 11
#define Kc 23
#define HWn (Hn * Wn)
#define PW 182                 // padded dim: 160 + 2*11
#define PP (PW * PW)
#define LAMc 0.15f
#define INVN (1.0f / (float)(Bn * HWn))
#define TJ 32                  // j-tile width (= lanes 0..31)
#define Gc 4                   // centers per thread (vertical)
#define TI 32                  // i-tile height = 8 ty-groups * Gc
#define NROW2 43               // staged rows per half-window block (32 + 11)
#define NREC2 (NROW2 * TJ)     // 1376 records in LDS (16 B each = 22.0 KB)
#define CEXP (-0.72134752f)    // -0.5 * log2(e)
#define CX   (14.42695041f)    // 20 * 0.72134752  (cross-term scale)
#define CA   (0.72134752f)
#define NPREP ((Bn * PP + 255) / 256)   // 259 prep blocks

__device__ __forceinline__ float wave_reduce64(float v) {
#pragma unroll
    for (int off = 32; off > 0; off >>= 1) v += __shfl_down(v, off, 64);
    return v;
}

// pack two floats as bf16 (rne) into one uint: a in high 16, b in low 16
__device__ __forceinline__ unsigned int bf16pk(float a, float b) {
    unsigned int ua = __float_as_uint(a), ub = __float_as_uint(b);
    ua += 0x7fffu + ((ua >> 16) & 1u);
    ub += 0x7fffu + ((ub >> 16) & 1u);
    return (ua & 0xffff0000u) | (ub >> 16);
}

// Fused: zero halo + softmax/pack interior + CE block-partials (pre-scaled) + zero out.
// Record uint4: [pk(p0,p1), pk(p2,mB), pk(q0,q1), pk(q2,0)]
//   p = raw image, mB = -72.13*sum(p^2) (fp32-computed, bf16-stored), q = src*y.
// exp2 exponent identity: -0.7213*sum((c-10p)^2) = (14.427*sum(c*p)) - A - B.
__global__ __launch_bounds__(256) void prep_kernel(
    const float* __restrict__ logit, const int* __restrict__ target,
    const float* __restrict__ image, const float* __restrict__ srcmap,
    const float* __restrict__ dstmap, uint4* __restrict__ gU4,
    float4* __restrict__ cvec, float* __restrict__ pc, float* __restrict__ out)
{
    int idx = blockIdx.x * 256 + threadIdx.x;
    float ce = 0.0f;
    if (idx < Bn * PP) {
        int b   = idx / PP;
        int rem = idx - b * PP;
        int ip  = rem / PW;
        int jp  = rem - ip * PW;
        int i = ip - SPANc, j = jp - SPANc;
        if ((unsigned)i < (unsigned)Hn && (unsigned)j < (unsigned)Wn) {
            int r = i * Wn + j;
            int p = b * HWn + r;
            const float* lg = logit + (size_t)b * Cn * HWn + r;
            float l0 = lg[0], l1 = lg[HWn], l2 = lg[2 * HWn];
            float m = fmaxf(l0, fmaxf(l1, l2));
            float e0 = __expf(l0 - m), e1 = __expf(l1 - m), e2 = __expf(l2 - m);
            float s = e0 + e1 + e2;
            float inv = 1.0f / s;
            float y0 = e0 * inv, y1 = e1 * inv, y2 = e2 * inv;
            float lse = m + __logf(s);

            const float* im = image + (size_t)b * 3 * HWn + r;
            float p0 = im[0], p1 = im[HWn], p2 = im[2 * HWn];
            float sv = srcmap[p];
            float dv = dstmap[p];

            float B = (p0 * p0 + p1 * p1 + p2 * p2) * (100.0f * CA);
            gU4[idx] = make_uint4(bf16pk(p0, p1), bf16pk(p2, -B),
                                  bf16pk(sv * y0, sv * y1), bf16pk(sv * y2, 0.0f));

            float md = LAMc * (1.0f - dv) * INVN;
            cvec[p] = make_float4(md * (1.0f - y0), md * (1.0f - y1),
                                  md * (1.0f - y2), 0.0f);

            int t = target[p];
            float lt = (t == 0) ? l0 : ((t == 1) ? l1 : l2);
            ce = (lse - lt) * dv * INVN;
        } else {
            gU4[idx] = make_uint4(0u, 0u, 0u, 0u);
        }
    }
    if (idx == 0) out[0] = 0.0f;   // gcrf launches after this completes (stream order)

    float v = wave_reduce64(ce);
    __shared__ float wsum[4];
    int tid = threadIdx.x;
    if ((tid & 63) == 0) wsum[tid >> 6] = v;
    __syncthreads();
    if (tid == 0) pc[blockIdx.x] = wsum[0] + wsum[1] + wsum[2] + wsum[3];
}

__device__ __forceinline__ void unpk(uint4 ru, float& p0, float& p1, float& p2,
                                     float& mB, float& q0, float& q1, float& q2) {
    p0 = __uint_as_float(ru.x & 0xffff0000u);
    p1 = __uint_as_float(ru.x << 16);
    p2 = __uint_as_float(ru.y & 0xffff0000u);
    mB = __uint_as_float(ru.y << 16);
    q0 = __uint_as_float(ru.z & 0xffff0000u);
    q1 = __uint_as_float(ru.z << 16);
    q2 = __uint_as_float(ru.w & 0xffff0000u);
}

// One tap: e = c.p chain seeded with mB; k = exp2(e + mA); acc. 8 VALU ops.
template<bool XY>
__device__ __forceinline__ void tap(float p0, float p1, float p2, float mB,
                                    float q0, float q1, float q2,
                                    float c0s, float c1s, float c2s, float mA,
                                    bool xy_on, float dy2, float dxv,
                                    float& e0, float& e1, float& e2)
{
    float e = fmaf(c0s, p0, fmaf(c1s, p1, fmaf(c2s, p2, mB)));
    float k = exp2f(e + mA);
    if constexpr (XY) {
        if (xy_on) k += exp2f(fmaf(dxv, dxv, dy2) * CEXP);   // few blocks only
    }
    e0 = fmaf(k, q0, e0);
    e1 = fmaf(k, q1, e1);
    e2 = fmaf(k, q2, e2);
}

// Half-window loop: DH=0 covers di in [0,11] (r' = c+d), DH=1 covers di in [12,22]
// (r' = c+d, d = di-11 in [1,11]). Thread-local staged rows r' = 0..14.
// Tap valid: (r' - c) in [DH, 11]  ->  c <= r' - DH  and  c >= r' - 11.
template<bool XY, int DH>
__device__ __forceinline__ void window_loop2(
    const uint4* sU4, int lbase,
    const float* c0s, const float* c1s, const float* c2s, const float* mA,
    bool xy_on, float dy2, float fi0, float eg[Gc][3])
{
#pragma unroll
    for (int r = DH; r < 4; ++r) {               // prologue (triangular)
        uint4 ru = sU4[lbase + r * TJ];
        float p0, p1, p2, mB, q0, q1, q2;
        unpk(ru, p0, p1, p2, mB, q0, q1, q2);
        float dxb = XY ? (fi0 - (fi0 + (float)(r - (DH ? 0 : SPANc))) * (1.0f / 6.0f)) : 0.0f;
#pragma unroll
        for (int c = 0; c < Gc; ++c) {
            if (c > r - DH) continue;
            tap<XY>(p0, p1, p2, mB, q0, q1, q2, c0s[c], c1s[c], c2s[c], mA[c],
                    xy_on, dy2, dxb + (float)c, eg[c][0], eg[c][1], eg[c][2]);
        }
    }
#pragma unroll 2
    for (int r = 4; r <= 11; ++r) {              // full rows: all 4 centers
        uint4 ru = sU4[lbase + r * TJ];
        float p0, p1, p2, mB, q0, q1, q2;
        unpk(ru, p0, p1, p2, mB, q0, q1, q2);
        float dxb = XY ? (fi0 - (fi0 + (float)(r - (DH ? 0 : SPANc))) * (1.0f / 6.0f)) : 0.0f;
#pragma unroll
        for (int c = 0; c < Gc; ++c) {
            tap<XY>(p0, p1, p2, mB, q0, q1, q2, c0s[c], c1s[c], c2s[c], mA[c],
                    xy_on, dy2, dxb + (float)c, eg[c][0], eg[c][1], eg[c][2]);
        }
    }
#pragma unroll
    for (int r = 12; r <= 14; ++r) {             // epilogue (triangular)
        uint4 ru = sU4[lbase + r * TJ];
        float p0, p1, p2, mB, q0, q1, q2;
        unpk(ru, p0, p1, p2, mB, q0, q1, q2);
        float dxb = XY ? (fi0 - (fi0 + (float)(r - (DH ? 0 : SPANc))) * (1.0f / 6.0f)) : 0.0f;
#pragma unroll
        for (int c = 0; c < Gc; ++c) {
            if (c < r - SPANc) continue;
            tap<XY>(p0, p1, p2, mB, q0, q1, q2, c0s[c], c1s[c], c2s[c], mA[c],
                    xy_on, dy2, dxb + (float)c, eg[c][0], eg[c][1], eg[c][2]);
        }
    }
}

// Window kernel, di-split. Grid: (5, 5*B, 46) = 2300 blocks. Block (32,8).
// One (dj, di-half) per block. Stage 43x32 uint4 records (22.0 KB LDS).
// LDS cap = 7 blocks/CU; launch_bounds requests 6 waves/SIMD (VGPR<=85) vs old 4.
// Each block float-atomicAdds its pre-scaled contribution into out[0].
__global__ __launch_bounds__(256, 6) void gcrf_kernel(
    const uint4* __restrict__ gU4, const float4* __restrict__ cvec,
    const float* __restrict__ pc, float* __restrict__ out)
{
    __shared__ uint4 sU4[NREC2];

    int tx = threadIdx.x;                 // 0..31 (j)
    int ty = threadIdx.y;                 // 0..7  (i-group)
    int tid = ty * TJ + tx;
    int jx = blockIdx.x;
    int j  = jx * TJ + tx;
    int by = blockIdx.y;
    int b  = by / 5;
    int it = by - b * 5;
    int i0g = it * TI + ty * Gc;          // first center row of this thread
    int zz = blockIdx.z;                  // 0..45
    int dh = (zz >= Kc) ? 1 : 0;          // di half: 0 -> di 0..11, 1 -> di 12..22
    int dj = zz - dh * Kc;                // 0..22
    int rbase = dh ? SPANc : 0;           // staged-row offset within tile

    size_t g0 = (size_t)b * PP + (size_t)(it * TI + rbase) * PW + (jx * TJ + dj);
    for (int n = tid; n < NREC2; n += 256) {
        int rr = n >> 5, cc = n & 31;
        sU4[n] = gU4[g0 + (size_t)rr * PW + cc];
    }
    __syncthreads();

    int lbase = ty * Gc * TJ + tx;        // LDS index of (local row ty*Gc, col tx)
    int crow = dh ? 0 : SPANc;            // center record offset in staged rows
    float c0s[Gc], c1s[Gc], c2s[Gc], mA[Gc];
#pragma unroll
    for (int c = 0; c < Gc; ++c) {
        uint4 cu = sU4[lbase + (c + crow) * TJ];
        float cc0 = __uint_as_float(cu.x & 0xffff0000u);
        float cc1 = __uint_as_float(cu.x << 16);
        float cc2 = __uint_as_float(cu.y & 0xffff0000u);
        c0s[c] = cc0 * CX; c1s[c] = cc1 * CX; c2s[c] = cc2 * CX;
        mA[c] = -CA * fmaf(cc0, cc0, fmaf(cc1, cc1, cc2 * cc2));
    }

    // k_xy < 2.3e-29 unless both i<16 and j<16 (source-bug form: d = c - p/6)
    bool xy_on = (j < 16) && (i0g < 16);
    float dy = (float)j - (float)(j + dj - SPANc) * (1.0f / 6.0f);
    float dy2 = dy * dy;
    float fi0 = (float)i0g;

    float eg[Gc][3];
#pragma unroll
    for (int c = 0; c < Gc; ++c) { eg[c][0] = 0.f; eg[c][1] = 0.f; eg[c][2] = 0.f; }

    if (jx == 0 && it == 0) {   // block-uniform: only blocks where xy_on can hold
        if (dh) window_loop2<true, 1>(sU4, lbase, c0s, c1s, c2s, mA, xy_on, dy2, fi0, eg);
        else    window_loop2<true, 0>(sU4, lbase, c0s, c1s, c2s, mA, xy_on, dy2, fi0, eg);
    } else {
        if (dh) window_loop2<false, 1>(sU4, lbase, c0s, c1s, c2s, mA, false, dy2, fi0, eg);
        else    window_loop2<false, 0>(sU4, lbase, c0s, c1s, c2s, mA, false, dy2, fi0, eg);
    }

    // epilogue: cvec already holds lam*(1-dst)*(1-y_c)/(B*HW)
    const float4* cv = cvec + ((size_t)b * HWn + (size_t)i0g * Wn + j);
    float contrib = 0.0f;
#pragma unroll
    for (int c = 0; c < Gc; ++c) {
        float4 t = cv[(size_t)c * Wn];
        contrib += eg[c][0] * t.x + eg[c][1] * t.y + eg[c][2] * t.z;
    }

    float v = wave_reduce64(contrib);
    __shared__ float wsum[4];
    if ((tid & 63) == 0) wsum[tid >> 6] = v;
    __syncthreads();
    if (tid == 0) atomicAdd(out, wsum[0] + wsum[1] + wsum[2] + wsum[3]);

    // designated block folds in the (pre-scaled) CE partial sums
    if (jx == 4 && by == 9 && zz == 45) {
        float s = 0.0f;
        if (tid < NPREP) s += pc[tid];
        if (tid + 256 < NPREP) s += pc[tid + 256];
        float v2 = wave_reduce64(s);
        __syncthreads();
        if ((tid & 63) == 0) wsum[tid >> 6] = v2;
        __syncthreads();
        if (tid == 0) atomicAdd(out, wsum[0] + wsum[1] + wsum[2] + wsum[3]);
    }
}

extern "C" void kernel_launch(void* const* d_in, const int* in_sizes, int n_in,
                              void* d_out, int out_size, void* d_ws, size_t ws_size,
                              hipStream_t stream)
{
    const float* logit  = (const float*)d_in[0];
    const int*   target = (const int*)d_in[1];
    const float* image  = (const float*)d_in[2];
    const float* srcmap = (const float*)d_in[3];
    const float* dstmap = (const float*)d_in[4];
    float* out = (float*)d_out;

    const size_t NRECG = (size_t)Bn * PP;   // 66,248 padded records
    float*  pc   = (float*)((char*)d_ws + 256);                  // 259 CE partials
    uint4*  gU4  = (uint4*)((char*)d_ws + 4096);
    float4* cvec = (float4*)((char*)d_ws + 4096 + NRECG * 16);

    prep_kernel<<<NPREP, 256, 0, stream>>>(logit, target, image, srcmap, dstmap,
                                           gU4, cvec, pc, out);
    dim3 grid(Wn / TJ, (Hn / TI) * Bn, 2 * Kc);
    dim3 blk(TJ, 8);
    gcrf_kernel<<<grid, blk, 0, stream>>>(gU4, cvec, pc, out);
}

// Round 2
// 85.091 us; speedup vs baseline: 1.1672x; 1.1672x over previous
//
#include <hip/hip_runtime.h>

#define Bn 2
#define Cn 3
#define Hn 160
#define Wn 160
#define SPANc 11
#define Kc 23
#define HWn (Hn * Wn)
#define PW 182                 // padded dim: 160 + 2*11
#define PP (PW * PW)
#define LAMc 0.15f
#define INVN (1.0f / (float)(Bn * HWn))
#define TJ 32                  // j-tile width (= lanes 0..31)
#define Gc 4                   // centers per thread (vertical)
#define TI 32                  // i-tile height = 8 ty-groups * Gc
#define NROW (TI + Kc - 1)     // 54 staged rows
#define NREC (NROW * TJ)       // 1728 records in LDS (16 B each = 27.6 KB)
#define CEXP (-0.72134752f)    // -0.5 * log2(e)
#define CX   (14.42695041f)    // 20 * 0.72134752  (cross-term scale)
#define CA   (0.72134752f)
#define NPREP ((Bn * PP + 255) / 256)   // 259 prep blocks

__device__ __forceinline__ float wave_reduce64(float v) {
#pragma unroll
    for (int off = 32; off > 0; off >>= 1) v += __shfl_down(v, off, 64);
    return v;
}

// pack two floats as bf16 (rne) into one uint: a in high 16, b in low 16
__device__ __forceinline__ unsigned int bf16pk(float a, float b) {
    unsigned int ua = __float_as_uint(a), ub = __float_as_uint(b);
    ua += 0x7fffu + ((ua >> 16) & 1u);
    ub += 0x7fffu + ((ub >> 16) & 1u);
    return (ua & 0xffff0000u) | (ub >> 16);
}

// Fused: zero halo + softmax/pack interior + CE block-partials (pre-scaled) + zero out.
// Record uint4: [pk(p0,p1), pk(p2,mB), pk(q0,q1), pk(q2,0)]
//   p = raw image, mB = -72.13*sum(p^2) (fp32-computed, bf16-stored), q = src*y.
// exp2 exponent identity: -0.7213*sum((c-10p)^2) = (14.427*sum(c*p)) - A - B.
__global__ __launch_bounds__(256) void prep_kernel(
    const float* __restrict__ logit, const int* __restrict__ target,
    const float* __restrict__ image, const float* __restrict__ srcmap,
    const float* __restrict__ dstmap, uint4* __restrict__ gU4,
    float4* __restrict__ cvec, float* __restrict__ pc, float* __restrict__ out)
{
    int idx = blockIdx.x * 256 + threadIdx.x;
    float ce = 0.0f;
    if (idx < Bn * PP) {
        int b   = idx / PP;
        int rem = idx - b * PP;
        int ip  = rem / PW;
        int jp  = rem - ip * PW;
        int i = ip - SPANc, j = jp - SPANc;
        if ((unsigned)i < (unsigned)Hn && (unsigned)j < (unsigned)Wn) {
            int r = i * Wn + j;
            int p = b * HWn + r;
            const float* lg = logit + (size_t)b * Cn * HWn + r;
            float l0 = lg[0], l1 = lg[HWn], l2 = lg[2 * HWn];
            float m = fmaxf(l0, fmaxf(l1, l2));
            float e0 = __expf(l0 - m), e1 = __expf(l1 - m), e2 = __expf(l2 - m);
            float s = e0 + e1 + e2;
            float inv = 1.0f / s;
            float y0 = e0 * inv, y1 = e1 * inv, y2 = e2 * inv;
            float lse = m + __logf(s);

            const float* im = image + (size_t)b * 3 * HWn + r;
            float p0 = im[0], p1 = im[HWn], p2 = im[2 * HWn];
            float sv = srcmap[p];
            float dv = dstmap[p];

            float B = (p0 * p0 + p1 * p1 + p2 * p2) * (100.0f * CA);
            gU4[idx] = make_uint4(bf16pk(p0, p1), bf16pk(p2, -B),
                                  bf16pk(sv * y0, sv * y1), bf16pk(sv * y2, 0.0f));

            float md = LAMc * (1.0f - dv) * INVN;
            cvec[p] = make_float4(md * (1.0f - y0), md * (1.0f - y1),
                                  md * (1.0f - y2), 0.0f);

            int t = target[p];
            float lt = (t == 0) ? l0 : ((t == 1) ? l1 : l2);
            ce = (lse - lt) * dv * INVN;
        } else {
            gU4[idx] = make_uint4(0u, 0u, 0u, 0u);
        }
    }
    if (idx == 0) out[0] = 0.0f;   // gcrf launches after this completes (stream order)

    float v = wave_reduce64(ce);
    __shared__ float wsum[4];
    int tid = threadIdx.x;
    if ((tid & 63) == 0) wsum[tid >> 6] = v;
    __syncthreads();
    if (tid == 0) pc[blockIdx.x] = wsum[0] + wsum[1] + wsum[2] + wsum[3];
}

__device__ __forceinline__ void unpk(uint4 ru, float& p0, float& p1, float& p2,
                                     float& mB, float& q0, float& q1, float& q2) {
    p0 = __uint_as_float(ru.x & 0xffff0000u);
    p1 = __uint_as_float(ru.x << 16);
    p2 = __uint_as_float(ru.y & 0xffff0000u);
    mB = __uint_as_float(ru.y << 16);
    q0 = __uint_as_float(ru.z & 0xffff0000u);
    q1 = __uint_as_float(ru.z << 16);
    q2 = __uint_as_float(ru.w & 0xffff0000u);
}

// One tap: e = c.p chain seeded with mB; k = exp2(e + mA); acc. 8 VALU ops.
// __builtin_amdgcn_exp2f == raw v_exp_f32 (1 ulp) — avoids any OCML range-
// handling wrapper on the hottest instruction in the kernel (27M execs).
template<bool XY>
__device__ __forceinline__ void tap(float p0, float p1, float p2, float mB,
                                    float q0, float q1, float q2,
                                    float c0s, float c1s, float c2s, float mA,
                                    bool xy_on, float dy2, float dxv,
                                    float& e0, float& e1, float& e2)
{
    float e = fmaf(c0s, p0, fmaf(c1s, p1, fmaf(c2s, p2, mB)));
    float k = __builtin_amdgcn_exp2f(e + mA);
    if constexpr (XY) {
        if (xy_on) k += __builtin_amdgcn_exp2f(fmaf(dxv, dxv, dy2) * CEXP);
    }
    e0 = fmaf(k, q0, e0);
    e1 = fmaf(k, q1, e1);
    e2 = fmaf(k, q2, e2);
}

template<bool XY>
__device__ __forceinline__ void row_taps(uint4 ru, int r,
    const float* c0s, const float* c1s, const float* c2s, const float* mA,
    bool xy_on, float dy2, float fi0, float eg[Gc][3], int clo, int chi)
{
    float p0, p1, p2, mB, q0, q1, q2;
    unpk(ru, p0, p1, p2, mB, q0, q1, q2);
    float dxb = XY ? (fi0 - (fi0 + (float)(r - SPANc)) * (1.0f / 6.0f)) : 0.0f;
#pragma unroll
    for (int c = 0; c < Gc; ++c) {
        if (c < clo || c > chi) continue;
        tap<XY>(p0, p1, p2, mB, q0, q1, q2, c0s[c], c1s[c], c2s[c], mA[c],
                xy_on, dy2, dxb + (float)c, eg[c][0], eg[c][1], eg[c][2]);
    }
}

// 3-phase window loop over staged LDS records. Main segment runs a depth-1
// rotating LDS prefetch (row r+1 issued while row r computes) at unroll 4.
template<bool XY>
__device__ __forceinline__ void window_loop(
    const uint4* sU4, int lbase,
    const float* c0s, const float* c1s, const float* c2s, const float* mA,
    bool xy_on, float dy2, float fi0, float eg[Gc][3])
{
#pragma unroll
    for (int r = 0; r < 3; ++r) {               // prologue (triangular): c <= r
        row_taps<XY>(sU4[lbase + r * TJ], r, c0s, c1s, c2s, mA,
                     xy_on, dy2, fi0, eg, 0, r);
    }
    uint4 cur = sU4[lbase + 3 * TJ];
#pragma unroll 4
    for (int r = 3; r <= 21; ++r) {             // full rows, pipelined
        uint4 nxt = sU4[lbase + (r + 1) * TJ];
        row_taps<XY>(cur, r, c0s, c1s, c2s, mA, xy_on, dy2, fi0, eg, 0, 3);
        cur = nxt;
    }
    row_taps<XY>(cur, 22, c0s, c1s, c2s, mA, xy_on, dy2, fi0, eg, 0, 3);
#pragma unroll
    for (int r = 23; r <= 25; ++r) {            // epilogue (triangular): c >= r-22
        row_taps<XY>(sU4[lbase + r * TJ], r, c0s, c1s, c2s, mA,
                     xy_on, dy2, fi0, eg, r - 22, 3);
    }
}

// Window kernel. Grid: (5, 5*B, 23) = 1150 blocks. Block (32,8). One dj per block.
// Stage 54x32 uint4 records (27.6 KB LDS, single ds_read_b128 per record).
// Each block float-atomicAdds its pre-scaled contribution into out[0] (no finalize
// dispatch, no device fence — R13 lesson). One designated non-XY block also reduces
// the 259 CE partials.
__global__ __launch_bounds__(256, 4) void gcrf_kernel(
    const uint4* __restrict__ gU4, const float4* __restrict__ cvec,
    const float* __restrict__ pc, float* __restrict__ out)
{
    __shared__ uint4 sU4[NREC];

    int tx = threadIdx.x;                 // 0..31 (j)
    int ty = threadIdx.y;                 // 0..7  (i-group)
    int tid = ty * TJ + tx;
    int jx = blockIdx.x;
    int j  = jx * TJ + tx;
    int by = blockIdx.y;
    int b  = by / 5;
    int it = by - b * 5;
    int i0g = it * TI + ty * Gc;          // first center row of this thread
    int dj = blockIdx.z;                  // 0..22

    size_t g0 = (size_t)b * PP + (size_t)(it * TI) * PW + (jx * TJ + dj);
    for (int n = tid; n < NREC; n += 256) {
        int rr = n >> 5, cc = n & 31;
        sU4[n] = gU4[g0 + (size_t)rr * PW + cc];
    }
    __syncthreads();

    int lbase = ty * Gc * TJ + tx;        // LDS index of (local row ty*Gc, col tx)
    float c0s[Gc], c1s[Gc], c2s[Gc], mA[Gc];
#pragma unroll
    for (int c = 0; c < Gc; ++c) {
        uint4 cu = sU4[lbase + (c + SPANc) * TJ];
        float cc0 = __uint_as_float(cu.x & 0xffff0000u);
        float cc1 = __uint_as_float(cu.x << 16);
        float cc2 = __uint_as_float(cu.y & 0xffff0000u);
        c0s[c] = cc0 * CX; c1s[c] = cc1 * CX; c2s[c] = cc2 * CX;
        mA[c] = -CA * fmaf(cc0, cc0, fmaf(cc1, cc1, cc2 * cc2));
    }

    // k_xy < 2.3e-29 unless both i<16 and j<16 (source-bug form: d = c - p/6)
    bool xy_on = (j < 16) && (i0g < 16);
    float dy = (float)j - (float)(j + dj - SPANc) * (1.0f / 6.0f);
    float dy2 = dy * dy;
    float fi0 = (float)i0g;

    float eg[Gc][3];
#pragma unroll
    for (int c = 0; c < Gc; ++c) { eg[c][0] = 0.f; eg[c][1] = 0.f; eg[c][2] = 0.f; }

    if (jx == 0 && it == 0) {   // block-uniform: only blocks where xy_on can hold
        window_loop<true>(sU4, lbase, c0s, c1s, c2s, mA, xy_on, dy2, fi0, eg);
    } else {
        window_loop<false>(sU4, lbase, c0s, c1s, c2s, mA, false, dy2, fi0, eg);
    }

    // epilogue: cvec already holds lam*(1-dst)*(1-y_c)/(B*HW)
    const float4* cv = cvec + ((size_t)b * HWn + (size_t)i0g * Wn + j);
    float contrib = 0.0f;
#pragma unroll
    for (int c = 0; c < Gc; ++c) {
        float4 t = cv[(size_t)c * Wn];
        contrib += eg[c][0] * t.x + eg[c][1] * t.y + eg[c][2] * t.z;
    }

    float v = wave_reduce64(contrib);
    __shared__ float wsum[4];
    if ((tid & 63) == 0) wsum[tid >> 6] = v;
    __syncthreads();
    if (tid == 0) atomicAdd(out, wsum[0] + wsum[1] + wsum[2] + wsum[3]);

    // designated non-XY block folds in the (pre-scaled) CE partial sums
    if (jx == 4 && by == 9 && dj == 22) {
        float s = 0.0f;
        if (tid < NPREP) s += pc[tid];
        if (tid + 256 < NPREP) s += pc[tid + 256];
        float v2 = wave_reduce64(s);
        __syncthreads();
        if ((tid & 63) == 0) wsum[tid >> 6] = v2;
        __syncthreads();
        if (tid == 0) atomicAdd(out, wsum[0] + wsum[1] + wsum[2] + wsum[3]);
    }
}

extern "C" void kernel_launch(void* const* d_in, const int* in_sizes, int n_in,
                              void* d_out, int out_size, void* d_ws, size_t ws_size,
                              hipStream_t stream)
{
    const float* logit  = (const float*)d_in[0];
    const int*   target = (const int*)d_in[1];
    const float* image  = (const float*)d_in[2];
    const float* srcmap = (const float*)d_in[3];
    const float* dstmap = (const float*)d_in[4];
    float* out = (float*)d_out;

    const size_t NRECG = (size_t)Bn * PP;   // 66,248 padded records
    float*  pc   = (float*)((char*)d_ws + 256);                  // 259 CE partials
    uint4*  gU4  = (uint4*)((char*)d_ws + 4096);
    float4* cvec = (float4*)((char*)d_ws + 4096 + NRECG * 16);

    prep_kernel<<<NPREP, 256, 0, stream>>>(logit, target, image, srcmap, dstmap,
                                           gU4, cvec, pc, out);
    dim3 grid(Wn / TJ, (Hn / TI) * Bn, Kc);
    dim3 blk(TJ, 8);
    gcrf_kernel<<<grid, blk, 0, stream>>>(gU4, cvec, pc, out);
}

// Round 3
// 81.717 us; speedup vs baseline: 1.2154x; 1.0413x over previous
//
#include <hip/hip_runtime.h>

#define Bn 2
#define Cn 3
#define Hn 160
#define Wn 160
#define SPANc 11
#define Kc 23
#define HWn (Hn * Wn)
#define PW 182                 // padded dim: 160 + 2*11
#define PP (PW * PW)
#define LAMc 0.15f
#define INVN (1.0f / (float)(Bn * HWn))
#define TJ 32                  // j-tile width (= lanes 0..31)
#define Gc 4                   // centers per thread (vertical)
#define TI 32                  // i-tile height = 8 ty-groups * Gc
#define NROW (TI + Kc - 1)     // 54 staged rows
#define NREC (NROW * TJ)       // 1728 records in LDS (16 B each = 27.6 KB)
#define CEXP (-0.72134752f)    // -0.5 * log2(e)
#define CX   (14.42695041f)    // 20 * 0.72134752  (cross-term scale)
#define CA   (0.72134752f)
#define NPREP ((Bn * PP + 255) / 256)   // 259 prep blocks
#define NCELL 64               // spread accumulator cells (256 B apart)
#define CELLSTRIDE 64          // floats between cells

__device__ __forceinline__ float wave_reduce64(float v) {
#pragma unroll
    for (int off = 32; off > 0; off >>= 1) v += __shfl_down(v, off, 64);
    return v;
}

// pack two floats as bf16 (rne) into one uint: a in high 16, b in low 16
__device__ __forceinline__ unsigned int bf16pk(float a, float b) {
    unsigned int ua = __float_as_uint(a), ub = __float_as_uint(b);
    ua += 0x7fffu + ((ua >> 16) & 1u);
    ub += 0x7fffu + ((ub >> 16) & 1u);
    return (ua & 0xffff0000u) | (ub >> 16);
}

// Fused: zero halo + softmax/pack interior + CE block-partials (pre-scaled) +
// zero the 64 spread cells. Record uint4: [pk(p0,p1), pk(p2,mB), pk(q0,q1), pk(q2,0)]
//   p = raw image, mB = -72.13*sum(p^2) (fp32-computed, bf16-stored), q = src*y.
// exp2 exponent identity: -0.7213*sum((c-10p)^2) = (14.427*sum(c*p)) - A - B.
__global__ __launch_bounds__(256) void prep_kernel(
    const float* __restrict__ logit, const int* __restrict__ target,
    const float* __restrict__ image, const float* __restrict__ srcmap,
    const float* __restrict__ dstmap, uint4* __restrict__ gU4,
    float4* __restrict__ cvec, float* __restrict__ pc, float* __restrict__ cells)
{
    int idx = blockIdx.x * 256 + threadIdx.x;
    float ce = 0.0f;
    if (idx < NCELL) cells[idx * CELLSTRIDE] = 0.0f;   // gcrf runs after (stream order)
    if (idx < Bn * PP) {
        int b   = idx / PP;
        int rem = idx - b * PP;
        int ip  = rem / PW;
        int jp  = rem - ip * PW;
        int i = ip - SPANc, j = jp - SPANc;
        if ((unsigned)i < (unsigned)Hn && (unsigned)j < (unsigned)Wn) {
            int r = i * Wn + j;
            int p = b * HWn + r;
            const float* lg = logit + (size_t)b * Cn * HWn + r;
            float l0 = lg[0], l1 = lg[HWn], l2 = lg[2 * HWn];
            float m = fmaxf(l0, fmaxf(l1, l2));
            float e0 = __expf(l0 - m), e1 = __expf(l1 - m), e2 = __expf(l2 - m);
            float s = e0 + e1 + e2;
            float inv = 1.0f / s;
            float y0 = e0 * inv, y1 = e1 * inv, y2 = e2 * inv;
            float lse = m + __logf(s);

            const float* im = image + (size_t)b * 3 * HWn + r;
            float p0 = im[0], p1 = im[HWn], p2 = im[2 * HWn];
            float sv = srcmap[p];
            float dv = dstmap[p];

            float B = (p0 * p0 + p1 * p1 + p2 * p2) * (100.0f * CA);
            gU4[idx] = make_uint4(bf16pk(p0, p1), bf16pk(p2, -B),
                                  bf16pk(sv * y0, sv * y1), bf16pk(sv * y2, 0.0f));

            float md = LAMc * (1.0f - dv) * INVN;
            cvec[p] = make_float4(md * (1.0f - y0), md * (1.0f - y1),
                                  md * (1.0f - y2), 0.0f);

            int t = target[p];
            float lt = (t == 0) ? l0 : ((t == 1) ? l1 : l2);
            ce = (lse - lt) * dv * INVN;
        } else {
            gU4[idx] = make_uint4(0u, 0u, 0u, 0u);
        }
    }

    float v = wave_reduce64(ce);
    __shared__ float wsum[4];
    int tid = threadIdx.x;
    if ((tid & 63) == 0) wsum[tid >> 6] = v;
    __syncthreads();
    if (tid == 0) pc[blockIdx.x] = wsum[0] + wsum[1] + wsum[2] + wsum[3];
}

__device__ __forceinline__ void unpk(uint4 ru, float& p0, float& p1, float& p2,
                                     float& mB, float& q0, float& q1, float& q2) {
    p0 = __uint_as_float(ru.x & 0xffff0000u);
    p1 = __uint_as_float(ru.x << 16);
    p2 = __uint_as_float(ru.y & 0xffff0000u);
    mB = __uint_as_float(ru.y << 16);
    q0 = __uint_as_float(ru.z & 0xffff0000u);
    q1 = __uint_as_float(ru.z << 16);
    q2 = __uint_as_float(ru.w & 0xffff0000u);
}

// One tap: e = c.p chain seeded with mB; k = exp2(e + mA); acc. 8 VALU ops.
template<bool XY>
__device__ __forceinline__ void tap(float p0, float p1, float p2, float mB,
                                    float q0, float q1, float q2,
                                    float c0s, float c1s, float c2s, float mA,
                                    bool xy_on, float dy2, float dxv,
                                    float& e0, float& e1, float& e2)
{
    float e = fmaf(c0s, p0, fmaf(c1s, p1, fmaf(c2s, p2, mB)));
    float k = __builtin_amdgcn_exp2f(e + mA);
    if constexpr (XY) {
        if (xy_on) k += __builtin_amdgcn_exp2f(fmaf(dxv, dxv, dy2) * CEXP);
    }
    e0 = fmaf(k, q0, e0);
    e1 = fmaf(k, q1, e1);
    e2 = fmaf(k, q2, e2);
}

template<bool XY>
__device__ __forceinline__ void row_taps(uint4 ru, int r,
    const float* c0s, const float* c1s, const float* c2s, const float* mA,
    bool xy_on, float dy2, float fi0, float eg[Gc][3], int clo, int chi)
{
    float p0, p1, p2, mB, q0, q1, q2;
    unpk(ru, p0, p1, p2, mB, q0, q1, q2);
    float dxb = XY ? (fi0 - (fi0 + (float)(r - SPANc)) * (1.0f / 6.0f)) : 0.0f;
#pragma unroll
    for (int c = 0; c < Gc; ++c) {
        if (c < clo || c > chi) continue;
        tap<XY>(p0, p1, p2, mB, q0, q1, q2, c0s[c], c1s[c], c2s[c], mA[c],
                xy_on, dy2, dxb + (float)c, eg[c][0], eg[c][1], eg[c][2]);
    }
}

// 3-phase window loop over staged LDS records. Main segment runs a depth-1
// rotating LDS prefetch (row r+1 issued while row r computes) at unroll 4.
template<bool XY>
__device__ __forceinline__ void window_loop(
    const uint4* sU4, int lbase,
    const float* c0s, const float* c1s, const float* c2s, const float* mA,
    bool xy_on, float dy2, float fi0, float eg[Gc][3])
{
#pragma unroll
    for (int r = 0; r < 3; ++r) {               // prologue (triangular): c <= r
        row_taps<XY>(sU4[lbase + r * TJ], r, c0s, c1s, c2s, mA,
                     xy_on, dy2, fi0, eg, 0, r);
    }
    uint4 cur = sU4[lbase + 3 * TJ];
#pragma unroll 4
    for (int r = 3; r <= 21; ++r) {             // full rows, pipelined
        uint4 nxt = sU4[lbase + (r + 1) * TJ];
        row_taps<XY>(cur, r, c0s, c1s, c2s, mA, xy_on, dy2, fi0, eg, 0, 3);
        cur = nxt;
    }
    row_taps<XY>(cur, 22, c0s, c1s, c2s, mA, xy_on, dy2, fi0, eg, 0, 3);
#pragma unroll
    for (int r = 23; r <= 25; ++r) {            // epilogue (triangular): c >= r-22
        row_taps<XY>(sU4[lbase + r * TJ], r, c0s, c1s, c2s, mA,
                     xy_on, dy2, fi0, eg, r - 22, 3);
    }
}

// Window kernel. Grid: (5, 5*B, 23) = 1150 blocks. Block (32,8). One dj per block.
// Stage 54x32 uint4 records (27.6 KB LDS, single ds_read_b128 per record).
// Reduction sink: atomicAdd into one of 64 spread cells (256 B apart) keyed by
// flat block id — ~18 atomics/cell on independent cachelines instead of 1150
// serialized same-address atomics on out[0].
__global__ __launch_bounds__(256, 4) void gcrf_kernel(
    const uint4* __restrict__ gU4, const float4* __restrict__ cvec,
    float* __restrict__ cells)
{
    __shared__ uint4 sU4[NREC];

    int tx = threadIdx.x;                 // 0..31 (j)
    int ty = threadIdx.y;                 // 0..7  (i-group)
    int tid = ty * TJ + tx;
    int jx = blockIdx.x;
    int j  = jx * TJ + tx;
    int by = blockIdx.y;
    int b  = by / 5;
    int it = by - b * 5;
    int i0g = it * TI + ty * Gc;          // first center row of this thread
    int dj = blockIdx.z;                  // 0..22

    size_t g0 = (size_t)b * PP + (size_t)(it * TI) * PW + (jx * TJ + dj);
    for (int n = tid; n < NREC; n += 256) {
        int rr = n >> 5, cc = n & 31;
        sU4[n] = gU4[g0 + (size_t)rr * PW + cc];
    }
    __syncthreads();

    int lbase = ty * Gc * TJ + tx;        // LDS index of (local row ty*Gc, col tx)
    float c0s[Gc], c1s[Gc], c2s[Gc], mA[Gc];
#pragma unroll
    for (int c = 0; c < Gc; ++c) {
        uint4 cu = sU4[lbase + (c + SPANc) * TJ];
        float cc0 = __uint_as_float(cu.x & 0xffff0000u);
        float cc1 = __uint_as_float(cu.x << 16);
        float cc2 = __uint_as_float(cu.y & 0xffff0000u);
        c0s[c] = cc0 * CX; c1s[c] = cc1 * CX; c2s[c] = cc2 * CX;
        mA[c] = -CA * fmaf(cc0, cc0, fmaf(cc1, cc1, cc2 * cc2));
    }

    // k_xy < 2.3e-29 unless both i<16 and j<16 (source-bug form: d = c - p/6)
    bool xy_on = (j < 16) && (i0g < 16);
    float dy = (float)j - (float)(j + dj - SPANc) * (1.0f / 6.0f);
    float dy2 = dy * dy;
    float fi0 = (float)i0g;

    float eg[Gc][3];
#pragma unroll
    for (int c = 0; c < Gc; ++c) { eg[c][0] = 0.f; eg[c][1] = 0.f; eg[c][2] = 0.f; }

    if (jx == 0 && it == 0) {   // block-uniform: only blocks where xy_on can hold
        window_loop<true>(sU4, lbase, c0s, c1s, c2s, mA, xy_on, dy2, fi0, eg);
    } else {
        window_loop<false>(sU4, lbase, c0s, c1s, c2s, mA, false, dy2, fi0, eg);
    }

    // epilogue: cvec already holds lam*(1-dst)*(1-y_c)/(B*HW)
    const float4* cv = cvec + ((size_t)b * HWn + (size_t)i0g * Wn + j);
    float contrib = 0.0f;
#pragma unroll
    for (int c = 0; c < Gc; ++c) {
        float4 t = cv[(size_t)c * Wn];
        contrib += eg[c][0] * t.x + eg[c][1] * t.y + eg[c][2] * t.z;
    }

    float v = wave_reduce64(contrib);
    __shared__ float wsum[4];
    if ((tid & 63) == 0) wsum[tid >> 6] = v;
    __syncthreads();
    if (tid == 0) {
        int bflat = (blockIdx.z * gridDim.y + blockIdx.y) * gridDim.x + blockIdx.x;
        atomicAdd(cells + (size_t)(bflat & (NCELL - 1)) * CELLSTRIDE,
                  wsum[0] + wsum[1] + wsum[2] + wsum[3]);
    }
}

// Single-wave finalize: sum 64 spread cells + 259 CE partials, plain-store out.
// Stream-ordered after gcrf; kernel boundary provides device-wide visibility.
__global__ __launch_bounds__(64) void finalize_kernel(
    const float* __restrict__ cells, const float* __restrict__ pc,
    float* __restrict__ out)
{
    int t = threadIdx.x;
    float s = cells[(size_t)t * CELLSTRIDE];
    for (int k = t; k < NPREP; k += 64) s += pc[k];
    float v = wave_reduce64(s);
    if (t == 0) out[0] = v;
}

extern "C" void kernel_launch(void* const* d_in, const int* in_sizes, int n_in,
                              void* d_out, int out_size, void* d_ws, size_t ws_size,
                              hipStream_t stream)
{
    const float* logit  = (const float*)d_in[0];
    const int*   target = (const int*)d_in[1];
    const float* image  = (const float*)d_in[2];
    const float* srcmap = (const float*)d_in[3];
    const float* dstmap = (const float*)d_in[4];
    float* out = (float*)d_out;

    const size_t NRECG = (size_t)Bn * PP;   // 66,248 padded records
    float*  pc    = (float*)((char*)d_ws + 256);                 // 259 CE partials
    float*  cells = (float*)((char*)d_ws + 4096);                // 64 cells, 256 B apart
    uint4*  gU4   = (uint4*)((char*)d_ws + 4096 + 16384);
    float4* cvec  = (float4*)((char*)d_ws + 4096 + 16384 + NRECG * 16);

    prep_kernel<<<NPREP, 256, 0, stream>>>(logit, target, image, srcmap, dstmap,
                                           gU4, cvec, pc, cells);
    dim3 grid(Wn / TJ, (Hn / TI) * Bn, Kc);
    dim3 blk(TJ, 8);
    gcrf_kernel<<<grid, blk, 0, stream>>>(gU4, cvec, cells);
    finalize_kernel<<<1, 64, 0, stream>>>(cells, pc, out);
}

// Round 4
// 79.585 us; speedup vs baseline: 1.2480x; 1.0268x over previous
//
#include <hip/hip_runtime.h>

#define Bn 2
#define Cn 3
#define Hn 160
#define Wn 160
#define SPANc 11
#define Kc 23
#define HWn (Hn * Wn)
#define PW 182                 // padded dim: 160 + 2*11
#define PP (PW * PW)
#define LAMc 0.15f
#define INVN (1.0f / (float)(Bn * HWn))
#define TJ 32                  // j-tile width (= lanes 0..31)
#define Gc 4                   // centers per thread (vertical)
#define TI 32                  // i-tile height = 8 ty-groups * Gc
#define NROW (TI + Kc - 1)     // 54 staged rows
#define NREC (NROW * TJ)       // 1728 records in LDS (16 B each = 27.6 KB)
#define CEXP (-0.72134752f)    // -0.5 * log2(e)
#define CX   (14.42695041f)    // 20 * 0.72134752  (cross-term scale)
#define CA   (0.72134752f)
#define NPREP ((Bn * PP + 255) / 256)   // 259 prep blocks
#define NCELL 64               // spread accumulator cells (256 B apart)
#define CELLSTRIDE 64          // floats between cells

__device__ __forceinline__ float wave_reduce64(float v) {
#pragma unroll
    for (int off = 32; off > 0; off >>= 1) v += __shfl_down(v, off, 64);
    return v;
}

// pack two floats as bf16 (rne) into one uint: a in high 16, b in low 16
__device__ __forceinline__ unsigned int bf16pk(float a, float b) {
    unsigned int ua = __float_as_uint(a), ub = __float_as_uint(b);
    ua += 0x7fffu + ((ua >> 16) & 1u);
    ub += 0x7fffu + ((ub >> 16) & 1u);
    return (ua & 0xffff0000u) | (ub >> 16);
}

// Fused: zero halo + softmax/pack interior + CE block-partials (pre-scaled) +
// zero the 64 spread cells. Record uint4: [pk(p0,p1), pk(p2,mB), pk(q0,q1), pk(q2,0)]
//   p = raw image, mB = -72.13*sum(p^2) (fp32-computed, bf16-stored), q = src*y.
// exp2 exponent identity: -0.7213*sum((c-10p)^2) = (14.427*sum(c*p)) - A - B.
__global__ __launch_bounds__(256) void prep_kernel(
    const float* __restrict__ logit, const int* __restrict__ target,
    const float* __restrict__ image, const float* __restrict__ srcmap,
    const float* __restrict__ dstmap, uint4* __restrict__ gU4,
    float4* __restrict__ cvec, float* __restrict__ pc, float* __restrict__ cells)
{
    int idx = blockIdx.x * 256 + threadIdx.x;
    float ce = 0.0f;
    if (idx < NCELL) cells[idx * CELLSTRIDE] = 0.0f;   // gcrf runs after (stream order)
    if (idx < Bn * PP) {
        int b   = idx / PP;
        int rem = idx - b * PP;
        int ip  = rem / PW;
        int jp  = rem - ip * PW;
        int i = ip - SPANc, j = jp - SPANc;
        if ((unsigned)i < (unsigned)Hn && (unsigned)j < (unsigned)Wn) {
            int r = i * Wn + j;
            int p = b * HWn + r;
            const float* lg = logit + (size_t)b * Cn * HWn + r;
            float l0 = lg[0], l1 = lg[HWn], l2 = lg[2 * HWn];
            float m = fmaxf(l0, fmaxf(l1, l2));
            float e0 = __expf(l0 - m), e1 = __expf(l1 - m), e2 = __expf(l2 - m);
            float s = e0 + e1 + e2;
            float inv = 1.0f / s;
            float y0 = e0 * inv, y1 = e1 * inv, y2 = e2 * inv;
            float lse = m + __logf(s);

            const float* im = image + (size_t)b * 3 * HWn + r;
            float p0 = im[0], p1 = im[HWn], p2 = im[2 * HWn];
            float sv = srcmap[p];
            float dv = dstmap[p];

            float B = (p0 * p0 + p1 * p1 + p2 * p2) * (100.0f * CA);
            gU4[idx] = make_uint4(bf16pk(p0, p1), bf16pk(p2, -B),
                                  bf16pk(sv * y0, sv * y1), bf16pk(sv * y2, 0.0f));

            float md = LAMc * (1.0f - dv) * INVN;
            cvec[p] = make_float4(md * (1.0f - y0), md * (1.0f - y1),
                                  md * (1.0f - y2), 0.0f);

            int t = target[p];
            float lt = (t == 0) ? l0 : ((t == 1) ? l1 : l2);
            ce = (lse - lt) * dv * INVN;
        } else {
            gU4[idx] = make_uint4(0u, 0u, 0u, 0u);
        }
    }

    float v = wave_reduce64(ce);
    __shared__ float wsum[4];
    int tid = threadIdx.x;
    if ((tid & 63) == 0) wsum[tid >> 6] = v;
    __syncthreads();
    if (tid == 0) pc[blockIdx.x] = wsum[0] + wsum[1] + wsum[2] + wsum[3];
}

__device__ __forceinline__ void unpk(uint4 ru, float& p0, float& p1, float& p2,
                                     float& mB, float& q0, float& q1, float& q2) {
    p0 = __uint_as_float(ru.x & 0xffff0000u);
    p1 = __uint_as_float(ru.x << 16);
    p2 = __uint_as_float(ru.y & 0xffff0000u);
    mB = __uint_as_float(ru.y << 16);
    q0 = __uint_as_float(ru.z & 0xffff0000u);
    q1 = __uint_as_float(ru.z << 16);
    q2 = __uint_as_float(ru.w & 0xffff0000u);
}

// One tap. Non-XY: kA-factored — k = exp2(c.p + mB); the per-center exp2(mA)
// is applied once in the epilogue (7 VALU ops, shorter dep chain).
// XY: exact form k = exp2(e + mA) (+ xy kernel); epilogue scale is 1.
template<bool XY>
__device__ __forceinline__ void tap(float p0, float p1, float p2, float mB,
                                    float q0, float q1, float q2,
                                    float c0s, float c1s, float c2s, float mA,
                                    bool xy_on, float dy2, float dxv,
                                    float& e0, float& e1, float& e2)
{
    float e = fmaf(c0s, p0, fmaf(c1s, p1, fmaf(c2s, p2, mB)));
    float k;
    if constexpr (XY) {
        k = __builtin_amdgcn_exp2f(e + mA);
        if (xy_on) k += __builtin_amdgcn_exp2f(fmaf(dxv, dxv, dy2) * CEXP);
    } else {
        k = __builtin_amdgcn_exp2f(e);
    }
    e0 = fmaf(k, q0, e0);
    e1 = fmaf(k, q1, e1);
    e2 = fmaf(k, q2, e2);
}

template<bool XY>
__device__ __forceinline__ void row_taps(uint4 ru, int r,
    const float* c0s, const float* c1s, const float* c2s, const float* mA,
    bool xy_on, float dy2, float fi0, float eg[Gc][3], int clo, int chi)
{
    float p0, p1, p2, mB, q0, q1, q2;
    unpk(ru, p0, p1, p2, mB, q0, q1, q2);
    float dxb = XY ? (fi0 - (fi0 + (float)(r - SPANc)) * (1.0f / 6.0f)) : 0.0f;
#pragma unroll
    for (int c = 0; c < Gc; ++c) {
        if (c < clo || c > chi) continue;
        tap<XY>(p0, p1, p2, mB, q0, q1, q2, c0s[c], c1s[c], c2s[c], mA[c],
                xy_on, dy2, dxb + (float)c, eg[c][0], eg[c][1], eg[c][2]);
    }
}

// 3-phase window loop over staged LDS records (R0-proven shape, no prefetch —
// prefetch measured neutral in R2; dropping it frees VGPRs for 5-block residency).
template<bool XY>
__device__ __forceinline__ void window_loop(
    const uint4* sU4, int lbase,
    const float* c0s, const float* c1s, const float* c2s, const float* mA,
    bool xy_on, float dy2, float fi0, float eg[Gc][3])
{
#pragma unroll
    for (int r = 0; r < 3; ++r) {               // prologue (triangular): c <= r
        row_taps<XY>(sU4[lbase + r * TJ], r, c0s, c1s, c2s, mA,
                     xy_on, dy2, fi0, eg, 0, r);
    }
#pragma unroll 2
    for (int r = 3; r <= 22; ++r) {             // full rows: all 4 centers
        row_taps<XY>(sU4[lbase + r * TJ], r, c0s, c1s, c2s, mA,
                     xy_on, dy2, fi0, eg, 0, 3);
    }
#pragma unroll
    for (int r = 23; r <= 25; ++r) {            // epilogue (triangular): c >= r-22
        row_taps<XY>(sU4[lbase + r * TJ], r, c0s, c1s, c2s, mA,
                     xy_on, dy2, fi0, eg, r - 22, 3);
    }
}

// Window kernel. Grid: (5, 5*B, 23) = 1150 blocks. Block (32,8). One dj per block.
// Stage 54x32 uint4 records (27.6 KB LDS -> LDS admits 5 blocks/CU).
// __launch_bounds__(256,5): cap VGPR ~102 so 5 blocks are co-resident -> all
// 1150 blocks fit on 256 CUs at once (capacity 1280), killing the 4.49-avg/
// 5-max imbalance tail of the 4-block config.
__global__ __launch_bounds__(256, 5) void gcrf_kernel(
    const uint4* __restrict__ gU4, const float4* __restrict__ cvec,
    float* __restrict__ cells)
{
    __shared__ uint4 sU4[NREC];

    int tx = threadIdx.x;                 // 0..31 (j)
    int ty = threadIdx.y;                 // 0..7  (i-group)
    int tid = ty * TJ + tx;
    int jx = blockIdx.x;
    int j  = jx * TJ + tx;
    int by = blockIdx.y;
    int b  = by / 5;
    int it = by - b * 5;
    int i0g = it * TI + ty * Gc;          // first center row of this thread
    int dj = blockIdx.z;                  // 0..22

    size_t g0 = (size_t)b * PP + (size_t)(it * TI) * PW + (jx * TJ + dj);
    for (int n = tid; n < NREC; n += 256) {
        int rr = n >> 5, cc = n & 31;
        sU4[n] = gU4[g0 + (size_t)rr * PW + cc];
    }
    __syncthreads();

    bool isxy = (jx == 0 && it == 0);     // block-uniform

    int lbase = ty * Gc * TJ + tx;        // LDS index of (local row ty*Gc, col tx)
    float c0s[Gc], c1s[Gc], c2s[Gc], mA[Gc], kAe[Gc];
#pragma unroll
    for (int c = 0; c < Gc; ++c) {
        uint4 cu = sU4[lbase + (c + SPANc) * TJ];
        float cc0 = __uint_as_float(cu.x & 0xffff0000u);
        float cc1 = __uint_as_float(cu.x << 16);
        float cc2 = __uint_as_float(cu.y & 0xffff0000u);
        c0s[c] = cc0 * CX; c1s[c] = cc1 * CX; c2s[c] = cc2 * CX;
        mA[c] = -CA * fmaf(cc0, cc0, fmaf(cc1, cc1, cc2 * cc2));
        kAe[c] = isxy ? 1.0f : __builtin_amdgcn_exp2f(mA[c]);
    }

    // k_xy < 2.3e-29 unless both i<16 and j<16 (source-bug form: d = c - p/6)
    bool xy_on = (j < 16) && (i0g < 16);
    float dy = (float)j - (float)(j + dj - SPANc) * (1.0f / 6.0f);
    float dy2 = dy * dy;
    float fi0 = (float)i0g;

    float eg[Gc][3];
#pragma unroll
    for (int c = 0; c < Gc; ++c) { eg[c][0] = 0.f; eg[c][1] = 0.f; eg[c][2] = 0.f; }

    if (isxy) {   // only blocks where xy_on can hold
        window_loop<true>(sU4, lbase, c0s, c1s, c2s, mA, xy_on, dy2, fi0, eg);
    } else {
        window_loop<false>(sU4, lbase, c0s, c1s, c2s, mA, false, dy2, fi0, eg);
    }

    // epilogue: cvec already holds lam*(1-dst)*(1-y_c)/(B*HW); kAe folds back
    // the per-center exp2(mA) removed from the non-XY tap.
    const float4* cv = cvec + ((size_t)b * HWn + (size_t)i0g * Wn + j);
    float contrib = 0.0f;
#pragma unroll
    for (int c = 0; c < Gc; ++c) {
        float4 t = cv[(size_t)c * Wn];
        float d = eg[c][0] * t.x + eg[c][1] * t.y + eg[c][2] * t.z;
        contrib = fmaf(kAe[c], d, contrib);
    }

    float v = wave_reduce64(contrib);
    __shared__ float wsum[4];
    if ((tid & 63) == 0) wsum[tid >> 6] = v;
    __syncthreads();
    if (tid == 0) {
        int bflat = (blockIdx.z * gridDim.y + blockIdx.y) * gridDim.x + blockIdx.x;
        atomicAdd(cells + (size_t)(bflat & (NCELL - 1)) * CELLSTRIDE,
                  wsum[0] + wsum[1] + wsum[2] + wsum[3]);
    }
}

// Single-wave finalize: sum 64 spread cells + 259 CE partials, plain-store out.
// Stream-ordered after gcrf; kernel boundary provides device-wide visibility.
__global__ __launch_bounds__(64) void finalize_kernel(
    const float* __restrict__ cells, const float* __restrict__ pc,
    float* __restrict__ out)
{
    int t = threadIdx.x;
    float s = cells[(size_t)t * CELLSTRIDE];
    for (int k = t; k < NPREP; k += 64) s += pc[k];
    float v = wave_reduce64(s);
    if (t == 0) out[0] = v;
}

extern "C" void kernel_launch(void* const* d_in, const int* in_sizes, int n_in,
                              void* d_out, int out_size, void* d_ws, size_t ws_size,
                              hipStream_t stream)
{
    const float* logit  = (const float*)d_in[0];
    const int*   target = (const int*)d_in[1];
    const float* image  = (const float*)d_in[2];
    const float* srcmap = (const float*)d_in[3];
    const float* dstmap = (const float*)d_in[4];
    float* out = (float*)d_out;

    const size_t NRECG = (size_t)Bn * PP;   // 66,248 padded records
    float*  pc    = (float*)((char*)d_ws + 256);                 // 259 CE partials
    float*  cells = (float*)((char*)d_ws + 4096);                // 64 cells, 256 B apart
    uint4*  gU4   = (uint4*)((char*)d_ws + 4096 + 16384);
    float4* cvec  = (float4*)((char*)d_ws + 4096 + 16384 + NRECG * 16);

    prep_kernel<<<NPREP, 256, 0, stream>>>(logit, target, image, srcmap, dstmap,
                                           gU4, cvec, pc, cells);
    dim3 grid(Wn / TJ, (Hn / TI) * Bn, Kc);
    dim3 blk(TJ, 8);
    gcrf_kernel<<<grid, blk, 0, stream>>>(gU4, cvec, cells);
    finalize_kernel<<<1, 64, 0, stream>>>(cells, pc, out);
}